// Round 5
// baseline (848.359 us; speedup 1.0000x reference)
//
#include <hip/hip_runtime.h>
#include <hip/hip_bf16.h>
#include <cstdint>
#include <cstddef>

#define N_NODES 65536
#define N_EDGES 1048576
#define N_GRAPHS 128
#define NPG 512
#define IN_DIM 64
#define HID 128
#define BN_EPS 1e-5f

typedef __attribute__((ext_vector_type(8))) short bf16x8;
typedef __attribute__((ext_vector_type(4))) float f32x4;
typedef __attribute__((ext_vector_type(8))) unsigned short u16x8;

// ---- bf16 helpers (RNE, matches v_cvt) ----
__device__ inline unsigned short f2bf(float f) {
  unsigned u = __builtin_bit_cast(unsigned, f);
  u = u + 0x7fffu + ((u >> 16) & 1u);
  return (unsigned short)(u >> 16);
}
__device__ inline float bf2f(unsigned short h) {
  unsigned u = ((unsigned)h) << 16;
  return __builtin_bit_cast(float, u);
}
// RNE hi + RNE residual lo (used where lo magnitude matters for dropped cross-terms)
__device__ inline void split_bf(float v, unsigned short& hi, unsigned short& lo) {
  hi = f2bf(v);
  lo = f2bf(v - bf2f(hi));
}
// cheap split: truncated hi (1 shift) + RNE residual lo. hi+lo sum quality identical
// (|v-hi-lo| <~ 2^-17 |v|); saves ~3 VALU ops/value vs RNE-hi.
__device__ inline void split_bf_fast(float v, unsigned short& hi, unsigned short& lo) {
  unsigned u = __builtin_bit_cast(unsigned, v);
  hi = (unsigned short)(u >> 16);
  float r = v - __builtin_bit_cast(float, u & 0xffff0000u);
  lo = f2bf(r);
}

// ---------------- CSR build ----------------
__global__ __launch_bounds__(256) void hist_kernel(const int* __restrict__ dst,
                                                   int* __restrict__ deg) {
  int e = blockIdx.x * 256 + threadIdx.x;
  if (e < N_EDGES) atomicAdd(&deg[dst[e]], 1);
}

__global__ __launch_bounds__(256) void dis_kernel(const int* __restrict__ deg,
                                                  float* __restrict__ dis) {
  int n = blockIdx.x * 256 + threadIdx.x;
  if (n < N_NODES) dis[n] = 1.0f / sqrtf((float)deg[n] + 1.0f);
}

__global__ __launch_bounds__(1024) void scan_kernel(const int* __restrict__ deg,
                                                    int* __restrict__ offsets,
                                                    int* __restrict__ cursor) {
  __shared__ int sums[1024];
  int t = threadIdx.x;
  int base = t * 64;
  const int4* dp = (const int4*)(deg + base);
  int s = 0;
#pragma unroll
  for (int i = 0; i < 16; i++) {
    int4 v = dp[i];
    s += v.x + v.y + v.z + v.w;
  }
  sums[t] = s;
  __syncthreads();
  for (int off = 1; off < 1024; off <<= 1) {
    int v = (t >= off) ? sums[t - off] : 0;
    __syncthreads();
    sums[t] += v;
    __syncthreads();
  }
  int run = (t == 0) ? 0 : sums[t - 1];
#pragma unroll
  for (int i = 0; i < 16; i++) {
    int4 v = dp[i];
    int idx = base + i * 4;
    offsets[idx] = run; cursor[idx] = run; run += v.x;
    offsets[idx + 1] = run; cursor[idx + 1] = run; run += v.y;
    offsets[idx + 2] = run; cursor[idx + 2] = run; run += v.z;
    offsets[idx + 3] = run; cursor[idx + 3] = run; run += v.w;
  }
  if (t == 1023) offsets[N_NODES] = run;
}

__global__ __launch_bounds__(256) void fill_kernel(const int* __restrict__ src,
                                                   const int* __restrict__ dst,
                                                   int* __restrict__ cursor,
                                                   int* __restrict__ csr) {
  int e = blockIdx.x * 256 + threadIdx.x;
  if (e < N_EDGES) {
    int d = dst[e];
    int slot = atomicAdd(&cursor[d], 1);
    csr[slot] = src[e];
  }
}

// ---------------- aggregation (gather over CSR), chunk-4 prefetch, split-bf16 out ------
__global__ __launch_bounds__(256) void agg64_kernel(const float* __restrict__ x,
                                                    const float* __restrict__ dis,
                                                    const int* __restrict__ offsets,
                                                    const int* __restrict__ csr,
                                                    unsigned short* __restrict__ zhi,
                                                    unsigned short* __restrict__ zlo) {
  int node = blockIdx.x * 4 + (threadIdx.x >> 6);
  int lane = threadIdx.x & 63;
  float dn = dis[node];
  float acc = x[(size_t)node * 64 + lane] * dn * dn;
  int beg = offsets[node], end = offsets[node + 1];
  int k = beg;
  for (; k + 4 <= end; k += 4) {
    int s0 = csr[k], s1 = csr[k + 1], s2 = csr[k + 2], s3 = csr[k + 3];
    float w0 = dn * dis[s0], w1 = dn * dis[s1], w2 = dn * dis[s2], w3 = dn * dis[s3];
    float v0 = x[(size_t)s0 * 64 + lane];
    float v1 = x[(size_t)s1 * 64 + lane];
    float v2 = x[(size_t)s2 * 64 + lane];
    float v3 = x[(size_t)s3 * 64 + lane];
    acc = fmaf(w0, v0, acc);
    acc = fmaf(w1, v1, acc);
    acc = fmaf(w2, v2, acc);
    acc = fmaf(w3, v3, acc);
  }
  for (; k < end; k++) {
    int s = csr[k];
    acc = fmaf(dn * dis[s], x[(size_t)s * 64 + lane], acc);
  }
  unsigned short h_, l_;
  split_bf(acc, h_, l_);
  zhi[(size_t)node * 64 + lane] = h_;
  zlo[(size_t)node * 64 + lane] = l_;
}

__global__ __launch_bounds__(256) void agg128_kernel(const float* __restrict__ h,
                                                     const float* __restrict__ dis,
                                                     const int* __restrict__ offsets,
                                                     const int* __restrict__ csr,
                                                     unsigned short* __restrict__ zhi,
                                                     unsigned short* __restrict__ zlo) {
  int node = blockIdx.x * 4 + (threadIdx.x >> 6);
  int lane = threadIdx.x & 63;
  float dn = dis[node];
  float sn = dn * dn;
  const float* hr = h + (size_t)node * 128;
  float a0 = hr[lane] * sn;
  float a1 = hr[lane + 64] * sn;
  int beg = offsets[node], end = offsets[node + 1];
  int k = beg;
  for (; k + 4 <= end; k += 4) {
    int s0 = csr[k], s1 = csr[k + 1], s2 = csr[k + 2], s3 = csr[k + 3];
    float w0 = dn * dis[s0], w1 = dn * dis[s1], w2 = dn * dis[s2], w3 = dn * dis[s3];
    const float* p0 = h + (size_t)s0 * 128;
    const float* p1 = h + (size_t)s1 * 128;
    const float* p2 = h + (size_t)s2 * 128;
    const float* p3 = h + (size_t)s3 * 128;
    float u0 = p0[lane], d0 = p0[lane + 64];
    float u1 = p1[lane], d1 = p1[lane + 64];
    float u2 = p2[lane], d2 = p2[lane + 64];
    float u3 = p3[lane], d3 = p3[lane + 64];
    a0 = fmaf(w0, u0, a0); a1 = fmaf(w0, d0, a1);
    a0 = fmaf(w1, u1, a0); a1 = fmaf(w1, d1, a1);
    a0 = fmaf(w2, u2, a0); a1 = fmaf(w2, d2, a1);
    a0 = fmaf(w3, u3, a0); a1 = fmaf(w3, d3, a1);
  }
  for (; k < end; k++) {
    int s = csr[k];
    float w = dn * dis[s];
    const float* hs = h + (size_t)s * 128;
    a0 = fmaf(w, hs[lane], a0);
    a1 = fmaf(w, hs[lane + 64], a1);
  }
  unsigned short h0, l0, h1, l1;
  split_bf(a0, h0, l0);
  split_bf(a1, h1, l1);
  zhi[(size_t)node * 128 + lane] = h0;
  zlo[(size_t)node * 128 + lane] = l0;
  zhi[(size_t)node * 128 + lane + 64] = h1;
  zlo[(size_t)node * 128 + lane + 64] = l1;
}

// ---------------- weight prep: fp32 W -> bf16 hi/lo in b-fragment layout ----------------
template <bool TRANS>
__global__ __launch_bounds__(256) void wprep_kernel(const float* __restrict__ W, int K, int O,
                                                    unsigned short* __restrict__ hi,
                                                    unsigned short* __restrict__ lo) {
  int idx = blockIdx.x * 256 + threadIdx.x;
  int KC = K / 32;
  int total = (O / 16) * KC * 64;
  if (idx >= total) return;
  int lane = idx & 63;
  int rest = idx >> 6;
  int kc = rest % KC;
  int nt = rest / KC;
  int n = nt * 16 + (lane & 15);
  int kb = kc * 32 + (lane >> 4) * 8;
  unsigned short* hp = hi + (size_t)idx * 8;
  unsigned short* lp = lo + (size_t)idx * 8;
#pragma unroll
  for (int j = 0; j < 8; j++) {
    int k = kb + j;
    float v = TRANS ? W[(size_t)n * K + k] : W[(size_t)k * O + n];
    unsigned short h_, l_;
    split_bf(v, h_, l_);
    hp[j] = h_;
    lp[j] = l_;
  }
}

// ---------------- MFMA GEMM ----------------
// SPLIT_OUT: write hi/lo bf16. GROUPED: single output buffer, per-row stride 2*O u16,
// organized as (O/32) groups of 64 u16: [32 hi][32 lo] — keeps hi+lo of a 32-value
// head-slice in ONE 128B cache line for the attention kernel's staged reads.
// DOPOOL: fuse the per-graph mean pool into the epilogue (this instantiation's 128 rows
// all belong to one graph): shfl-reduce col sums over quads -> LDS partials -> atomicAdd.
template <int K, int O, bool DOBN, bool DORELU, bool SPLIT_OUT, bool GROUPED,
          bool DOPOOL = false>
__global__ __launch_bounds__(256) void gemm_mfma(
    const unsigned short* __restrict__ Ahi, const unsigned short* __restrict__ Alo,
    const unsigned short* __restrict__ Whi, const unsigned short* __restrict__ Wlo,
    const float* __restrict__ bias,
    const float* __restrict__ gamma, const float* __restrict__ beta,
    const float* __restrict__ mean, const float* __restrict__ var,
    float* __restrict__ Cf, unsigned short* __restrict__ Chi,
    unsigned short* __restrict__ Clo, float* __restrict__ Pool = nullptr) {
  constexpr int KC = K / 32;
  int wave = threadIdx.x >> 6;
  int lane = threadIdx.x & 63;
  int m0 = blockIdx.x * 128 + wave * 32;
  int o0 = blockIdx.y * 128;
  int mrow = lane & 15;
  int kseg = (lane >> 4) * 8;

  f32x4 acc[2][8];
#pragma unroll
  for (int mt = 0; mt < 2; mt++)
#pragma unroll
    for (int nt = 0; nt < 8; nt++) acc[mt][nt] = (f32x4)0.0f;

#pragma unroll
  for (int kc = 0; kc < KC; kc++) {
    bf16x8 ah[2], al[2];
#pragma unroll
    for (int mt = 0; mt < 2; mt++) {
      size_t aoff = (size_t)(m0 + mt * 16 + mrow) * K + kc * 32 + kseg;
      ah[mt] = *(const bf16x8*)(Ahi + aoff);
      al[mt] = *(const bf16x8*)(Alo + aoff);
    }
#pragma unroll
    for (int nt = 0; nt < 8; nt++) {
      size_t foff = (((size_t)(blockIdx.y * 8 + nt) * KC + kc) * 64 + lane) * 8;
      bf16x8 bh = *(const bf16x8*)(Whi + foff);
      bf16x8 bl = *(const bf16x8*)(Wlo + foff);
#pragma unroll
      for (int mt = 0; mt < 2; mt++) {
        acc[mt][nt] = __builtin_amdgcn_mfma_f32_16x16x32_bf16(ah[mt], bh, acc[mt][nt], 0, 0, 0);
        acc[mt][nt] = __builtin_amdgcn_mfma_f32_16x16x32_bf16(ah[mt], bl, acc[mt][nt], 0, 0, 0);
        acc[mt][nt] = __builtin_amdgcn_mfma_f32_16x16x32_bf16(al[mt], bh, acc[mt][nt], 0, 0, 0);
        acc[mt][nt] = __builtin_amdgcn_mfma_f32_16x16x32_bf16(al[mt], bl, acc[mt][nt], 0, 0, 0);
      }
    }
  }

  int ccol = lane & 15;
  int crow0 = (lane >> 4) * 4;
  float colsum[8];
  if constexpr (DOPOOL) {
#pragma unroll
    for (int nt = 0; nt < 8; nt++) colsum[nt] = 0.0f;
  }
#pragma unroll
  for (int nt = 0; nt < 8; nt++) {
    int c = o0 + nt * 16 + ccol;
    float sc, cb;
    float b = bias[c];
    if (DOBN) {
      sc = gamma[c] * rsqrtf(var[c] + BN_EPS);
      cb = (b - mean[c]) * sc + beta[c];
    } else {
      sc = 1.0f;
      cb = b;
    }
#pragma unroll
    for (int mt = 0; mt < 2; mt++) {
#pragma unroll
      for (int r = 0; r < 4; r++) {
        float v = fmaf(acc[mt][nt][r], sc, cb);
        if (DORELU) v = fmaxf(v, 0.0f);
        size_t row = (size_t)(m0 + mt * 16 + crow0 + r);
        if (SPLIT_OUT) {
          unsigned short h_, l_;
          split_bf(v, h_, l_);
          if (GROUPED) {
            size_t base = row * (size_t)(2 * O) + (size_t)(((c >> 5) << 6) + (c & 31));
            Chi[base] = h_;
            Chi[base + 32] = l_;
          } else {
            Chi[row * O + c] = h_;
            Clo[row * O + c] = l_;
          }
        } else {
          Cf[row * O + c] = v;
        }
        if constexpr (DOPOOL) colsum[nt] += v;
      }
    }
  }
  if constexpr (DOPOOL) {
    __shared__ float pb[4][128];
#pragma unroll
    for (int nt = 0; nt < 8; nt++) {
      float cs = colsum[nt];
      cs += __shfl_xor(cs, 16, 64);
      cs += __shfl_xor(cs, 32, 64);
      if ((lane >> 4) == 0) pb[wave][nt * 16 + ccol] = cs;
    }
    __syncthreads();
    int tt = threadIdx.x;
    if (tt < 128) {
      float s2 = pb[0][tt] + pb[1][tt] + pb[2][tt] + pb[3][tt];
      int gg = blockIdx.x >> 2;  // 4 blocks of 128 rows per graph
      atomicAdd(&Pool[gg * 128 + tt], s2 * (1.0f / NPG));
    }
  }
}

// ---------------- key-norm max per (graph, head), grouped split input ----------------
__global__ __launch_bounds__(256) void knorm_kernel(const unsigned short* __restrict__ qvs,
                                                    float* __restrict__ kmax2) {
  int g = blockIdx.x >> 2;
  int h = blockIdx.x & 3;
  size_t gbase = (size_t)g * NPG;
  float best = 0.0f;
#pragma unroll
  for (int r = 0; r < 2; r++) {
    int j = r * 256 + threadIdx.x;
    size_t base = (gbase + j) * 768 + (size_t)(4 + h) * 64;  // K group for head h
    float s = 0.0f;
#pragma unroll
    for (int i = 0; i < 4; i++) {
      u16x8 hh = *(const u16x8*)(qvs + base + i * 8);
      u16x8 ll = *(const u16x8*)(qvs + base + 32 + i * 8);
#pragma unroll
      for (int jj = 0; jj < 8; jj++) {
        float v = bf2f(hh[jj]) + bf2f(ll[jj]);
        s = fmaf(v, v, s);
      }
    }
    best = fmaxf(best, s);
  }
#pragma unroll
  for (int off = 32; off >= 1; off >>= 1)
    best = fmaxf(best, __shfl_xor(best, off, 64));
  __shared__ float red[4];
  int wave = threadIdx.x >> 6;
  if ((threadIdx.x & 63) == 0) red[wave] = best;
  __syncthreads();
  if (threadIdx.x == 0) {
    float m = fmaxf(fmaxf(red[0], red[1]), fmaxf(red[2], red[3]));
    kmax2[blockIdx.x] = m;
  }
}

// ---------------- attention via MFMA (flash-style, single pass, C-S bound) --------------
// grid: 1024 blocks = (graph, head, half), XCD-swizzled so one graph's 8 blocks land on
// one XCD (shared K/V lines L2-hit; partial C-line writes from the 4 heads merge).
// block 256 thr / 4 waves; wave owns 64 queries. QKV in GROUPED split layout.
// K/V double-buffered in LDS, ONE barrier per chunk (loads for c+1 issue first and are
// consumed after the compute phase — T14). P-buffer stride 44 u16: write banks
// 88*quad mod 32 = {0,24,16,8} partition exactly (2-way free vs 4-way at stride 40);
// read bank-starts 22*l15 mod 32 all-distinct (20*l15 collided at l15 vs l15+8).
// T5: s_setprio(1) wraps the MFMA clusters.
__global__ __launch_bounds__(256, 2) void attn_mfma_kernel(
    const unsigned short* __restrict__ qvs, const float* __restrict__ kmax2,
    unsigned short* __restrict__ ohi, unsigned short* __restrict__ olo) {
  int wb = ((blockIdx.x & 7) << 7) | (blockIdx.x >> 3);
  int g = wb >> 3;
  int h = (wb >> 1) & 3;
  int half = wb & 1;
  int t = threadIdx.x;
  int wave = t >> 6;
  int lane = t & 63;
  int quad = lane >> 4;
  int l15 = lane & 15;
  size_t gbase = (size_t)g * NPG;
  int qb = half * 256 + wave * 64;

  const float cf = 0.17677669529663687f * 1.4426950408889634f;  // scale*log2(e)

  __shared__ unsigned short Kh[2][32][40] __attribute__((aligned(16)));
  __shared__ unsigned short Kl[2][32][40] __attribute__((aligned(16)));
  __shared__ unsigned short Vh[2][33][40] __attribute__((aligned(16)));  // row 32 = ones
  __shared__ unsigned short Vl[2][33][40] __attribute__((aligned(16)));
  __shared__ char wbuf[4][11264] __attribute__((aligned(16)));  // per-wave P / O-transpose

  unsigned short* Ph = (unsigned short*)wbuf[wave];        // [64][44] bf16
  unsigned short* Pl = Ph + 64 * 44;                       // [64][44] bf16
  float* Ot = (float*)wbuf[wave];                          // [64][36] f32 (epilogue/qn)

  // ---- Q fragments: direct pre-split loads + |q|^2 (reconstructed = what MFMA sees) ----
  bf16x8 qh[4], ql[4];
  float qn2p[4];
#pragma unroll
  for (int mt = 0; mt < 4; mt++) {
    size_t qoff = (gbase + qb + mt * 16 + l15) * 768 + (size_t)h * 64 + quad * 8;
    u16x8 hh = *(const u16x8*)(qvs + qoff);
    u16x8 ll = *(const u16x8*)(qvs + qoff + 32);
    qh[mt] = __builtin_bit_cast(bf16x8, hh);
    ql[mt] = __builtin_bit_cast(bf16x8, ll);
    float s = 0.0f;
#pragma unroll
    for (int j = 0; j < 8; j++) {
      float v = bf2f(hh[j]) + bf2f(ll[j]);
      s = fmaf(v, v, s);
    }
    s += __shfl_xor(s, 16);
    s += __shfl_xor(s, 32);
    qn2p[mt] = s;  // full |q|^2 for query mt*16 + l15
  }
  // exchange |q|^2 so each lane gets the bound for its C-layout rows
  if (quad == 0) {
#pragma unroll
    for (int mt = 0; mt < 4; mt++) Ot[mt * 16 + l15] = qn2p[mt];
  }
  float km2 = kmax2[g * 4 + h];
  float Mq[4][4];
#pragma unroll
  for (int mt = 0; mt < 4; mt++)
#pragma unroll
    for (int r = 0; r < 4; r++)
      Mq[mt][r] = cf * sqrtf(Ot[mt * 16 + quad * 4 + r] * km2);

  f32x4 Oa[4][3];
#pragma unroll
  for (int mt = 0; mt < 4; mt++)
#pragma unroll
    for (int nt = 0; nt < 3; nt++) Oa[mt][nt] = (f32x4)0.0f;

  // ones rows for the l-column (dv=32), both buffers, once: threads 64-71
  if (t >= 64 && t < 72) {
    int u = t - 64;
    int bsel = u >> 2;
    int i = u & 3;
    u16x8 ones;
#pragma unroll
    for (int j = 0; j < 8; j++) ones[j] = 0x3F80;
    *(u16x8*)&Vh[bsel][32][i * 8] = ones;
  }

  // staging roles: threads 128-255 stage K (32 keys x 4 dim-segments);
  // threads 0-63 stage V^T (8 key-blocks x 8 dim-blocks)
  bool isK = (t >= 128);
  bool isV = (t < 64);
  u16x8 kreg_h, kreg_l;
  ushort4 vreg_h[4], vreg_l[4];
  int kkey = 0, kds = 0, vkeyb = 0, vdvb = 0;
  if (isK) {
    int t2 = t - 128;
    kkey = t2 >> 2;
    kds = (t2 & 3) * 8;
  } else if (isV) {
    vkeyb = (t & 7) * 4;
    vdvb = (t >> 3) * 4;
  }

  auto load_chunk = [&](int c) {
    if (isK) {
      size_t ko = (gbase + (size_t)(c * 32 + kkey)) * 768 + (size_t)(4 + h) * 64 + kds;
      kreg_h = *(const u16x8*)(qvs + ko);
      kreg_l = *(const u16x8*)(qvs + ko + 32);
    } else if (isV) {
#pragma unroll
      for (int r = 0; r < 4; r++) {
        size_t vo = (gbase + (size_t)(c * 32 + vkeyb + r)) * 768 + (size_t)(8 + h) * 64 + vdvb;
        vreg_h[r] = *(const ushort4*)(qvs + vo);
        vreg_l[r] = *(const ushort4*)(qvs + vo + 32);
      }
    }
  };

  auto stage_chunk = [&](int bsel) {
    if (isK) {
      *(u16x8*)&Kh[bsel][kkey][kds] = kreg_h;
      *(u16x8*)&Kl[bsel][kkey][kds] = kreg_l;
    } else if (isV) {
      unsigned short ha[4][4], la[4][4];
#pragma unroll
      for (int r = 0; r < 4; r++) {
        *(ushort4*)&ha[r][0] = vreg_h[r];
        *(ushort4*)&la[r][0] = vreg_l[r];
      }
#pragma unroll
      for (int c2 = 0; c2 < 4; c2++) {
        ushort4 hv, lv;
        hv.x = ha[0][c2]; hv.y = ha[1][c2]; hv.z = ha[2][c2]; hv.w = ha[3][c2];
        lv.x = la[0][c2]; lv.y = la[1][c2]; lv.z = la[2][c2]; lv.w = la[3][c2];
        *(ushort4*)&Vh[bsel][vdvb + c2][vkeyb] = hv;
        *(ushort4*)&Vl[bsel][vdvb + c2][vkeyb] = lv;
      }
    }
  };

  // prologue: chunk 0 into buf 0
  load_chunk(0);
  stage_chunk(0);
  __syncthreads();

  int p = 0;
  for (int c = 0; c < 16; c++) {
    // ---- issue next chunk's loads first: latency hides under the compute below ----
    if (c < 15) load_chunk(c + 1);

    // ---- QK^T -> S -> P (scale folded into fma; cheap trunc-split; store to LDS) ----
#pragma unroll
    for (int nt = 0; nt < 2; nt++) {
      bf16x8 bkh = *(const bf16x8*)&Kh[p][nt * 16 + l15][quad * 8];
      bf16x8 bkl = *(const bf16x8*)&Kl[p][nt * 16 + l15][quad * 8];
#pragma unroll
      for (int mt = 0; mt < 4; mt++) {
        f32x4 S = (f32x4)0.0f;
        __builtin_amdgcn_s_setprio(1);
        S = __builtin_amdgcn_mfma_f32_16x16x32_bf16(qh[mt], bkh, S, 0, 0, 0);
        S = __builtin_amdgcn_mfma_f32_16x16x32_bf16(qh[mt], bkl, S, 0, 0, 0);
        S = __builtin_amdgcn_mfma_f32_16x16x32_bf16(ql[mt], bkh, S, 0, 0, 0);
        S = __builtin_amdgcn_mfma_f32_16x16x32_bf16(ql[mt], bkl, S, 0, 0, 0);
        __builtin_amdgcn_s_setprio(0);
#pragma unroll
        for (int r = 0; r < 4; r++) {
          float pexp = __builtin_exp2f(fmaf(S[r], cf, -Mq[mt][r]));
          unsigned short hi_, lo_;
          split_bf_fast(pexp, hi_, lo_);
          int row = mt * 16 + quad * 4 + r;
          Ph[row * 44 + nt * 16 + l15] = hi_;
          Pl[row * 44 + nt * 16 + l15] = lo_;
        }
      }
    }
    // ---- PV: P A-frags x V^T B-frags ----
    bf16x8 pah[4], pal[4];
#pragma unroll
    for (int mt = 0; mt < 4; mt++) {
      pah[mt] = *(const bf16x8*)&Ph[(mt * 16 + l15) * 44 + quad * 8];
      pal[mt] = *(const bf16x8*)&Pl[(mt * 16 + l15) * 44 + quad * 8];
    }
    __builtin_amdgcn_s_setprio(1);
#pragma unroll
    for (int nt = 0; nt < 3; nt++) {
      bf16x8 bvh = *(const bf16x8*)&Vh[p][nt * 16 + l15][quad * 8];
      if (nt < 2) {
        bf16x8 bvl = *(const bf16x8*)&Vl[p][nt * 16 + l15][quad * 8];
#pragma unroll
        for (int mt = 0; mt < 4; mt++) {
          Oa[mt][nt] = __builtin_amdgcn_mfma_f32_16x16x32_bf16(pah[mt], bvh, Oa[mt][nt], 0, 0, 0);
          Oa[mt][nt] = __builtin_amdgcn_mfma_f32_16x16x32_bf16(pah[mt], bvl, Oa[mt][nt], 0, 0, 0);
          Oa[mt][nt] = __builtin_amdgcn_mfma_f32_16x16x32_bf16(pal[mt], bvh, Oa[mt][nt], 0, 0, 0);
        }
      } else {
#pragma unroll
        for (int mt = 0; mt < 4; mt++) {
          Oa[mt][nt] = __builtin_amdgcn_mfma_f32_16x16x32_bf16(pah[mt], bvh, Oa[mt][nt], 0, 0, 0);
          Oa[mt][nt] = __builtin_amdgcn_mfma_f32_16x16x32_bf16(pal[mt], bvh, Oa[mt][nt], 0, 0, 0);
        }
      }
    }
    __builtin_amdgcn_s_setprio(0);

    // ---- write prefetched chunk c+1 into the other buffer, then single barrier ----
    if (c < 15) stage_chunk(p ^ 1);
    __syncthreads();
    p ^= 1;
  }

  // ---- epilogue: transpose O through per-wave LDS, normalize, split-bf16 store ----
  // (per-wave buffer; wave-lockstep ds ordering makes this barrier-free)
#pragma unroll
  for (int mt = 0; mt < 4; mt++) {
#pragma unroll
    for (int r = 0; r < 4; r++) {
      int row = mt * 16 + quad * 4 + r;
      Ot[row * 36 + l15] = Oa[mt][0][r];
      Ot[row * 36 + 16 + l15] = Oa[mt][1][r];
      if (l15 == 0) Ot[row * 36 + 32] = Oa[mt][2][r];  // l = ones-column
    }
  }
  {
    int row = lane;  // wave's query row
    float inv = 1.0f / Ot[row * 36 + 32];
    size_t node = gbase + qb + row;
    u16x8 vh, vl;
#pragma unroll
    for (int seg = 0; seg < 4; seg++) {
#pragma unroll
      for (int j = 0; j < 8; j++) {
        unsigned short hi_, lo_;
        split_bf_fast(Ot[row * 36 + seg * 8 + j] * inv, hi_, lo_);
        vh[j] = hi_;
        vl[j] = lo_;
      }
      *(u16x8*)(ohi + node * 128 + h * 32 + seg * 8) = vh;
      *(u16x8*)(olo + node * 128 + h * 32 + seg * 8) = vl;
    }
  }
}

extern "C" void kernel_launch(void* const* d_in, const int* in_sizes, int n_in,
                              void* d_out, int out_size, void* d_ws, size_t ws_size,
                              hipStream_t stream) {
  (void)in_sizes; (void)n_in; (void)out_size; (void)ws_size;
  const float* x          = (const float*)d_in[0];
  const float* W0         = (const float*)d_in[1];
  const float* b0         = (const float*)d_in[2];
  const float* Wh         = (const float*)d_in[3];
  const float* bh         = (const float*)d_in[4];
  const float* bn_gamma   = (const float*)d_in[5];
  const float* bn_beta    = (const float*)d_in[6];
  const float* bn_mean    = (const float*)d_in[7];
  const float* bn_var     = (const float*)d_in[8];
  const float* attn_in_w  = (const float*)d_in[9];
  const float* attn_in_b  = (const float*)d_in[10];
  const float* attn_out_w = (const float*)d_in[11];
  const float* attn_out_b = (const float*)d_in[12];
  const int* edge_index   = (const int*)d_in[13];
  const int* src = edge_index;
  const int* dst = edge_index + N_EDGES;

  char* ws = (char*)d_ws;
  size_t off = 0;
  auto alloc = [&](size_t bytes) -> void* {
    void* p = ws + off;
    off += (bytes + 255) & ~(size_t)255;
    return p;
  };
  int*   deg     = (int*)alloc((size_t)N_NODES * 4);
  int*   offsets = (int*)alloc((size_t)(N_NODES + 1) * 4);
  int*   cursor  = (int*)alloc((size_t)N_NODES * 4);
  int*   csr     = (int*)alloc((size_t)N_EDGES * 4);
  float* dis     = (float*)alloc((size_t)N_NODES * 4);
  float* bufA    = (float*)alloc((size_t)N_NODES * HID * 4);   // h fp32; later f_hi/f_lo
  unsigned short* zhi = (unsigned short*)alloc((size_t)N_NODES * HID * 2);  // also o_hi
  unsigned short* zlo = (unsigned short*)alloc((size_t)N_NODES * HID * 2);  // also o_lo
  unsigned short* qvs = (unsigned short*)alloc((size_t)N_NODES * 768 * 2);  // qkv grouped hi/lo
  float* kmax2   = (float*)alloc((size_t)N_GRAPHS * 4 * 4);
  unsigned short* w0h = (unsigned short*)alloc(8192 * 2);
  unsigned short* w0l = (unsigned short*)alloc(8192 * 2);
  unsigned short* whh[3], *whl[3];
  for (int i = 0; i < 3; i++) {
    whh[i] = (unsigned short*)alloc(16384 * 2);
    whl[i] = (unsigned short*)alloc(16384 * 2);
  }
  unsigned short* wqh = (unsigned short*)alloc(49152 * 2);
  unsigned short* wql = (unsigned short*)alloc(49152 * 2);
  unsigned short* woh = (unsigned short*)alloc(16384 * 2);
  unsigned short* wol = (unsigned short*)alloc(16384 * 2);

  unsigned short* fhi = (unsigned short*)bufA;
  unsigned short* flo = fhi + (size_t)N_NODES * HID;

  float* fin = (float*)d_out;                       // [N, HID]
  float* emb = fin + (size_t)N_NODES * HID;         // [G, HID]

  hipMemsetAsync(deg, 0, (size_t)N_NODES * 4, stream);
  hipMemsetAsync(emb, 0, (size_t)N_GRAPHS * HID * 4, stream);
  hist_kernel<<<N_EDGES / 256, 256, 0, stream>>>(dst, deg);
  dis_kernel<<<N_NODES / 256, 256, 0, stream>>>(deg, dis);
  scan_kernel<<<1, 1024, 0, stream>>>(deg, offsets, cursor);
  fill_kernel<<<N_EDGES / 256, 256, 0, stream>>>(src, dst, cursor, csr);

  wprep_kernel<false><<<4, 256, 0, stream>>>(W0, 64, 128, w0h, w0l);
  for (int i = 0; i < 3; i++)
    wprep_kernel<false><<<8, 256, 0, stream>>>(Wh + (size_t)i * HID * HID, 128, 128,
                                               whh[i], whl[i]);
  wprep_kernel<true><<<24, 256, 0, stream>>>(attn_in_w, 128, 384, wqh, wql);
  wprep_kernel<true><<<8, 256, 0, stream>>>(attn_out_w, 128, 128, woh, wol);

  dim3 ggrid(N_NODES / 128, 1);
  agg64_kernel<<<N_NODES / 4, 256, 0, stream>>>(x, dis, offsets, csr, zhi, zlo);
  gemm_mfma<64, 128, true, true, false, false><<<ggrid, 256, 0, stream>>>(
      zhi, zlo, w0h, w0l, b0, bn_gamma, bn_beta, bn_mean, bn_var, bufA, nullptr, nullptr);
  for (int L = 0; L < 2; L++) {
    agg128_kernel<<<N_NODES / 4, 256, 0, stream>>>(bufA, dis, offsets, csr, zhi, zlo);
    gemm_mfma<128, 128, true, true, false, false><<<ggrid, 256, 0, stream>>>(
        zhi, zlo, whh[L], whl[L], bh + (size_t)L * HID,
        bn_gamma + (size_t)(L + 1) * HID, bn_beta + (size_t)(L + 1) * HID,
        bn_mean + (size_t)(L + 1) * HID, bn_var + (size_t)(L + 1) * HID,
        bufA, nullptr, nullptr);
  }
  agg128_kernel<<<N_NODES / 4, 256, 0, stream>>>(bufA, dis, offsets, csr, zhi, zlo);
  gemm_mfma<128, 128, true, true, true, false><<<ggrid, 256, 0, stream>>>(
      zhi, zlo, whh[2], whl[2], bh + (size_t)2 * HID,
      bn_gamma + (size_t)3 * HID, bn_beta + (size_t)3 * HID,
      bn_mean + (size_t)3 * HID, bn_var + (size_t)3 * HID,
      nullptr, fhi, flo);
  dim3 qgrid(N_NODES / 128, 3);
  gemm_mfma<128, 384, false, false, true, true><<<qgrid, 256, 0, stream>>>(
      fhi, flo, wqh, wql, attn_in_b, nullptr, nullptr, nullptr, nullptr,
      nullptr, qvs, nullptr);
  knorm_kernel<<<N_GRAPHS * 4, 256, 0, stream>>>(qvs, kmax2);
  attn_mfma_kernel<<<N_GRAPHS * 4 * 2, 256, 0, stream>>>(qvs, kmax2, zhi, zlo);
  gemm_mfma<128, 128, false, false, false, false, true><<<ggrid, 256, 0, stream>>>(
      zhi, zlo, woh, wol, attn_out_b, nullptr, nullptr, nullptr, nullptr,
      fin, nullptr, nullptr, emb);
}

// Round 6
// 806.166 us; speedup vs baseline: 1.0523x; 1.0523x over previous
//
#include <hip/hip_runtime.h>
#include <hip/hip_bf16.h>
#include <cstdint>
#include <cstddef>

#define N_NODES 65536
#define N_EDGES 1048576
#define N_GRAPHS 128
#define NPG 512
#define IN_DIM 64
#define HID 128
#define BN_EPS 1e-5f

typedef __attribute__((ext_vector_type(8))) short bf16x8;
typedef __attribute__((ext_vector_type(4))) float f32x4;
typedef __attribute__((ext_vector_type(8))) unsigned short u16x8;
typedef __attribute__((ext_vector_type(4))) unsigned int u32x4;

// ---- bf16 helpers (RNE, matches v_cvt) ----
__device__ inline unsigned short f2bf(float f) {
  unsigned u = __builtin_bit_cast(unsigned, f);
  u = u + 0x7fffu + ((u >> 16) & 1u);
  return (unsigned short)(u >> 16);
}
__device__ inline float bf2f(unsigned short h) {
  unsigned u = ((unsigned)h) << 16;
  return __builtin_bit_cast(float, u);
}
// RNE hi + RNE residual lo (used where lo magnitude matters for dropped cross-terms)
__device__ inline void split_bf(float v, unsigned short& hi, unsigned short& lo) {
  hi = f2bf(v);
  lo = f2bf(v - bf2f(hi));
}
// cheap split: truncated hi (1 shift) + RNE residual lo. hi+lo sum quality identical
// (|v-hi-lo| <~ 2^-17 |v|); saves ~3 VALU ops/value vs RNE-hi.
__device__ inline void split_bf_fast(float v, unsigned short& hi, unsigned short& lo) {
  unsigned u = __builtin_bit_cast(unsigned, v);
  hi = (unsigned short)(u >> 16);
  float r = v - __builtin_bit_cast(float, u & 0xffff0000u);
  lo = f2bf(r);
}

// ---------------- CSR build ----------------
__global__ __launch_bounds__(256) void hist_kernel(const int* __restrict__ dst,
                                                   int* __restrict__ deg) {
  int e = blockIdx.x * 256 + threadIdx.x;
  if (e < N_EDGES) atomicAdd(&deg[dst[e]], 1);
}

__global__ __launch_bounds__(256) void dis_kernel(const int* __restrict__ deg,
                                                  float* __restrict__ dis) {
  int n = blockIdx.x * 256 + threadIdx.x;
  if (n < N_NODES) dis[n] = 1.0f / sqrtf((float)deg[n] + 1.0f);
}

__global__ __launch_bounds__(1024) void scan_kernel(const int* __restrict__ deg,
                                                    int* __restrict__ offsets,
                                                    int* __restrict__ cursor) {
  __shared__ int sums[1024];
  int t = threadIdx.x;
  int base = t * 64;
  const int4* dp = (const int4*)(deg + base);
  int s = 0;
#pragma unroll
  for (int i = 0; i < 16; i++) {
    int4 v = dp[i];
    s += v.x + v.y + v.z + v.w;
  }
  sums[t] = s;
  __syncthreads();
  for (int off = 1; off < 1024; off <<= 1) {
    int v = (t >= off) ? sums[t - off] : 0;
    __syncthreads();
    sums[t] += v;
    __syncthreads();
  }
  int run = (t == 0) ? 0 : sums[t - 1];
#pragma unroll
  for (int i = 0; i < 16; i++) {
    int4 v = dp[i];
    int idx = base + i * 4;
    offsets[idx] = run; cursor[idx] = run; run += v.x;
    offsets[idx + 1] = run; cursor[idx + 1] = run; run += v.y;
    offsets[idx + 2] = run; cursor[idx + 2] = run; run += v.z;
    offsets[idx + 3] = run; cursor[idx + 3] = run; run += v.w;
  }
  if (t == 1023) offsets[N_NODES] = run;
}

__global__ __launch_bounds__(256) void fill_kernel(const int* __restrict__ src,
                                                   const int* __restrict__ dst,
                                                   int* __restrict__ cursor,
                                                   int* __restrict__ csr) {
  int e = blockIdx.x * 256 + threadIdx.x;
  if (e < N_EDGES) {
    int d = dst[e];
    int slot = atomicAdd(&cursor[d], 1);
    csr[slot] = src[e];
  }
}

// ---------------- aggregation (gather over CSR), chunk-4 prefetch, split-bf16 out ------
__global__ __launch_bounds__(256) void agg64_kernel(const float* __restrict__ x,
                                                    const float* __restrict__ dis,
                                                    const int* __restrict__ offsets,
                                                    const int* __restrict__ csr,
                                                    unsigned short* __restrict__ zhi,
                                                    unsigned short* __restrict__ zlo) {
  int node = blockIdx.x * 4 + (threadIdx.x >> 6);
  int lane = threadIdx.x & 63;
  float dn = dis[node];
  float acc = x[(size_t)node * 64 + lane] * dn * dn;
  int beg = offsets[node], end = offsets[node + 1];
  int k = beg;
  for (; k + 4 <= end; k += 4) {
    int s0 = csr[k], s1 = csr[k + 1], s2 = csr[k + 2], s3 = csr[k + 3];
    float w0 = dn * dis[s0], w1 = dn * dis[s1], w2 = dn * dis[s2], w3 = dn * dis[s3];
    float v0 = x[(size_t)s0 * 64 + lane];
    float v1 = x[(size_t)s1 * 64 + lane];
    float v2 = x[(size_t)s2 * 64 + lane];
    float v3 = x[(size_t)s3 * 64 + lane];
    acc = fmaf(w0, v0, acc);
    acc = fmaf(w1, v1, acc);
    acc = fmaf(w2, v2, acc);
    acc = fmaf(w3, v3, acc);
  }
  for (; k < end; k++) {
    int s = csr[k];
    acc = fmaf(dn * dis[s], x[(size_t)s * 64 + lane], acc);
  }
  unsigned short h_, l_;
  split_bf(acc, h_, l_);
  zhi[(size_t)node * 64 + lane] = h_;
  zlo[(size_t)node * 64 + lane] = l_;
}

__global__ __launch_bounds__(256) void agg128_kernel(const float* __restrict__ h,
                                                     const float* __restrict__ dis,
                                                     const int* __restrict__ offsets,
                                                     const int* __restrict__ csr,
                                                     unsigned short* __restrict__ zhi,
                                                     unsigned short* __restrict__ zlo) {
  int node = blockIdx.x * 4 + (threadIdx.x >> 6);
  int lane = threadIdx.x & 63;
  float dn = dis[node];
  float sn = dn * dn;
  const float* hr = h + (size_t)node * 128;
  float a0 = hr[lane] * sn;
  float a1 = hr[lane + 64] * sn;
  int beg = offsets[node], end = offsets[node + 1];
  int k = beg;
  for (; k + 4 <= end; k += 4) {
    int s0 = csr[k], s1 = csr[k + 1], s2 = csr[k + 2], s3 = csr[k + 3];
    float w0 = dn * dis[s0], w1 = dn * dis[s1], w2 = dn * dis[s2], w3 = dn * dis[s3];
    const float* p0 = h + (size_t)s0 * 128;
    const float* p1 = h + (size_t)s1 * 128;
    const float* p2 = h + (size_t)s2 * 128;
    const float* p3 = h + (size_t)s3 * 128;
    float u0 = p0[lane], d0 = p0[lane + 64];
    float u1 = p1[lane], d1 = p1[lane + 64];
    float u2 = p2[lane], d2 = p2[lane + 64];
    float u3 = p3[lane], d3 = p3[lane + 64];
    a0 = fmaf(w0, u0, a0); a1 = fmaf(w0, d0, a1);
    a0 = fmaf(w1, u1, a0); a1 = fmaf(w1, d1, a1);
    a0 = fmaf(w2, u2, a0); a1 = fmaf(w2, d2, a1);
    a0 = fmaf(w3, u3, a0); a1 = fmaf(w3, d3, a1);
  }
  for (; k < end; k++) {
    int s = csr[k];
    float w = dn * dis[s];
    const float* hs = h + (size_t)s * 128;
    a0 = fmaf(w, hs[lane], a0);
    a1 = fmaf(w, hs[lane + 64], a1);
  }
  unsigned short h0, l0, h1, l1;
  split_bf(a0, h0, l0);
  split_bf(a1, h1, l1);
  zhi[(size_t)node * 128 + lane] = h0;
  zlo[(size_t)node * 128 + lane] = l0;
  zhi[(size_t)node * 128 + lane + 64] = h1;
  zlo[(size_t)node * 128 + lane + 64] = l1;
}

// ---------------- weight prep: fp32 W -> bf16 hi/lo in b-fragment layout ----------------
template <bool TRANS>
__global__ __launch_bounds__(256) void wprep_kernel(const float* __restrict__ W, int K, int O,
                                                    unsigned short* __restrict__ hi,
                                                    unsigned short* __restrict__ lo) {
  int idx = blockIdx.x * 256 + threadIdx.x;
  int KC = K / 32;
  int total = (O / 16) * KC * 64;
  if (idx >= total) return;
  int lane = idx & 63;
  int rest = idx >> 6;
  int kc = rest % KC;
  int nt = rest / KC;
  int n = nt * 16 + (lane & 15);
  int kb = kc * 32 + (lane >> 4) * 8;
  unsigned short* hp = hi + (size_t)idx * 8;
  unsigned short* lp = lo + (size_t)idx * 8;
#pragma unroll
  for (int j = 0; j < 8; j++) {
    int k = kb + j;
    float v = TRANS ? W[(size_t)n * K + k] : W[(size_t)k * O + n];
    unsigned short h_, l_;
    split_bf(v, h_, l_);
    hp[j] = h_;
    lp[j] = l_;
  }
}

// ---------------- MFMA GEMM ----------------
// SPLIT_OUT: write hi/lo bf16. GROUPED: single output buffer, per-row stride 2*O u16,
// organized as (O/32) groups of 64 u16: [32 hi][32 lo] — keeps hi+lo of a 32-value
// head-slice in ONE 128B cache line for the attention kernel's staged reads.
// DOPOOL: fuse the per-graph mean pool into the epilogue.
template <int K, int O, bool DOBN, bool DORELU, bool SPLIT_OUT, bool GROUPED,
          bool DOPOOL = false>
__global__ __launch_bounds__(256) void gemm_mfma(
    const unsigned short* __restrict__ Ahi, const unsigned short* __restrict__ Alo,
    const unsigned short* __restrict__ Whi, const unsigned short* __restrict__ Wlo,
    const float* __restrict__ bias,
    const float* __restrict__ gamma, const float* __restrict__ beta,
    const float* __restrict__ mean, const float* __restrict__ var,
    float* __restrict__ Cf, unsigned short* __restrict__ Chi,
    unsigned short* __restrict__ Clo, float* __restrict__ Pool = nullptr) {
  constexpr int KC = K / 32;
  int wave = threadIdx.x >> 6;
  int lane = threadIdx.x & 63;
  int m0 = blockIdx.x * 128 + wave * 32;
  int o0 = blockIdx.y * 128;
  int mrow = lane & 15;
  int kseg = (lane >> 4) * 8;

  f32x4 acc[2][8];
#pragma unroll
  for (int mt = 0; mt < 2; mt++)
#pragma unroll
    for (int nt = 0; nt < 8; nt++) acc[mt][nt] = (f32x4)0.0f;

#pragma unroll
  for (int kc = 0; kc < KC; kc++) {
    bf16x8 ah[2], al[2];
#pragma unroll
    for (int mt = 0; mt < 2; mt++) {
      size_t aoff = (size_t)(m0 + mt * 16 + mrow) * K + kc * 32 + kseg;
      ah[mt] = *(const bf16x8*)(Ahi + aoff);
      al[mt] = *(const bf16x8*)(Alo + aoff);
    }
#pragma unroll
    for (int nt = 0; nt < 8; nt++) {
      size_t foff = (((size_t)(blockIdx.y * 8 + nt) * KC + kc) * 64 + lane) * 8;
      bf16x8 bh = *(const bf16x8*)(Whi + foff);
      bf16x8 bl = *(const bf16x8*)(Wlo + foff);
#pragma unroll
      for (int mt = 0; mt < 2; mt++) {
        acc[mt][nt] = __builtin_amdgcn_mfma_f32_16x16x32_bf16(ah[mt], bh, acc[mt][nt], 0, 0, 0);
        acc[mt][nt] = __builtin_amdgcn_mfma_f32_16x16x32_bf16(ah[mt], bl, acc[mt][nt], 0, 0, 0);
        acc[mt][nt] = __builtin_amdgcn_mfma_f32_16x16x32_bf16(al[mt], bh, acc[mt][nt], 0, 0, 0);
        acc[mt][nt] = __builtin_amdgcn_mfma_f32_16x16x32_bf16(al[mt], bl, acc[mt][nt], 0, 0, 0);
      }
    }
  }

  int ccol = lane & 15;
  int crow0 = (lane >> 4) * 4;
  float colsum[8];
  if constexpr (DOPOOL) {
#pragma unroll
    for (int nt = 0; nt < 8; nt++) colsum[nt] = 0.0f;
  }
#pragma unroll
  for (int nt = 0; nt < 8; nt++) {
    int c = o0 + nt * 16 + ccol;
    float sc, cb;
    float b = bias[c];
    if (DOBN) {
      sc = gamma[c] * rsqrtf(var[c] + BN_EPS);
      cb = (b - mean[c]) * sc + beta[c];
    } else {
      sc = 1.0f;
      cb = b;
    }
#pragma unroll
    for (int mt = 0; mt < 2; mt++) {
#pragma unroll
      for (int r = 0; r < 4; r++) {
        float v = fmaf(acc[mt][nt][r], sc, cb);
        if (DORELU) v = fmaxf(v, 0.0f);
        size_t row = (size_t)(m0 + mt * 16 + crow0 + r);
        if (SPLIT_OUT) {
          unsigned short h_, l_;
          split_bf(v, h_, l_);
          if (GROUPED) {
            size_t base = row * (size_t)(2 * O) + (size_t)(((c >> 5) << 6) + (c & 31));
            Chi[base] = h_;
            Chi[base + 32] = l_;
          } else {
            Chi[row * O + c] = h_;
            Clo[row * O + c] = l_;
          }
        } else {
          Cf[row * O + c] = v;
        }
        if constexpr (DOPOOL) colsum[nt] += v;
      }
    }
  }
  if constexpr (DOPOOL) {
    __shared__ float pb[4][128];
#pragma unroll
    for (int nt = 0; nt < 8; nt++) {
      float cs = colsum[nt];
      cs += __shfl_xor(cs, 16, 64);
      cs += __shfl_xor(cs, 32, 64);
      if ((lane >> 4) == 0) pb[wave][nt * 16 + ccol] = cs;
    }
    __syncthreads();
    int tt = threadIdx.x;
    if (tt < 128) {
      float s2 = pb[0][tt] + pb[1][tt] + pb[2][tt] + pb[3][tt];
      int gg = blockIdx.x >> 2;  // 4 blocks of 128 rows per graph
      atomicAdd(&Pool[gg * 128 + tt], s2 * (1.0f / NPG));
    }
  }
}

// ---------------- key-norm max per (graph, head), grouped split input ----------------
__global__ __launch_bounds__(256) void knorm_kernel(const unsigned short* __restrict__ qvs,
                                                    float* __restrict__ kmax2) {
  int g = blockIdx.x >> 2;
  int h = blockIdx.x & 3;
  size_t gbase = (size_t)g * NPG;
  float best = 0.0f;
#pragma unroll
  for (int r = 0; r < 2; r++) {
    int j = r * 256 + threadIdx.x;
    size_t base = (gbase + j) * 768 + (size_t)(4 + h) * 64;  // K group for head h
    float s = 0.0f;
#pragma unroll
    for (int i = 0; i < 4; i++) {
      u16x8 hh = *(const u16x8*)(qvs + base + i * 8);
      u16x8 ll = *(const u16x8*)(qvs + base + 32 + i * 8);
#pragma unroll
      for (int jj = 0; jj < 8; jj++) {
        float v = bf2f(hh[jj]) + bf2f(ll[jj]);
        s = fmaf(v, v, s);
      }
    }
    best = fmaxf(best, s);
  }
#pragma unroll
  for (int off = 32; off >= 1; off >>= 1)
    best = fmaxf(best, __shfl_xor(best, off, 64));
  __shared__ float red[4];
  int wave = threadIdx.x >> 6;
  if ((threadIdx.x & 63) == 0) red[wave] = best;
  __syncthreads();
  if (threadIdx.x == 0) {
    float m = fmaxf(fmaxf(red[0], red[1]), fmaxf(red[2], red[3]));
    kmax2[blockIdx.x] = m;
  }
}

// ---------------- attention via MFMA (flash-style, swapped-QK, in-register P) ----------
// grid: 1024 blocks = (graph, head, half), XCD-swizzled; block 256 thr / 4 waves;
// wave owns 64 queries. QKV in GROUPED split layout. K/V double-buffered, one barrier
// per chunk, next-chunk loads issued before compute (T14).
//
// SWAPPED QK (T12): S' = mfma(A=K, B=Q) puts each lane's P values on its OWN query
// (col = l15 = query); no LDS P buffer at all. Lane (quad,l15) gets, per (mt,nt),
// keys K-row nt*16+quad*4+r. K rows are PRE-PERMUTED at staging so that after a fixed
// 3-shuffle exchange the lane holds exactly the PV A-frag keys (quad*8..quad*8+7):
//   K-row (nt,q',r) holds chunk key kphys = 8*(q'^p) + 2p + (r&1), p=(nt<<1)|(r>>1).
//   Packet slot p (u32 of 2 bf16, pair r01/r23 per nt) routes lane.quad -> quad^p via
//   __shfl_xor(16/32/48); received slot p = frag u32 p = keys 8*quad+2p+{0,1}.
// V^T stays in natural chunk-key order (= pv index). Mq is lane-local (|q|^2 of own
// query), so the prologue LDS exchange is gone too. LDS = K/V (20.8KB) + one shared
// 9.2KB epilogue scratch (turn-taken by waves) = 30KB -> 3-4 blocks/CU.
__global__ __launch_bounds__(256, 2) void attn_mfma_kernel(
    const unsigned short* __restrict__ qvs, const float* __restrict__ kmax2,
    unsigned short* __restrict__ ohi, unsigned short* __restrict__ olo) {
  int wb = ((blockIdx.x & 7) << 7) | (blockIdx.x >> 3);
  int g = wb >> 3;
  int h = (wb >> 1) & 3;
  int half = wb & 1;
  int t = threadIdx.x;
  int wave = t >> 6;
  int lane = t & 63;
  int quad = lane >> 4;
  int l15 = lane & 15;
  size_t gbase = (size_t)g * NPG;
  int qb = half * 256 + wave * 64;

  const float cf = 0.17677669529663687f * 1.4426950408889634f;  // scale*log2(e)

  __shared__ unsigned short Kh[2][32][40] __attribute__((aligned(16)));
  __shared__ unsigned short Kl[2][32][40] __attribute__((aligned(16)));
  __shared__ unsigned short Vh[2][33][40] __attribute__((aligned(16)));  // row 32 = ones
  __shared__ unsigned short Vl[2][33][40] __attribute__((aligned(16)));
  __shared__ float Ot[64 * 36] __attribute__((aligned(16)));  // epilogue scratch (turn-taken)

  // ---- Q fragments + lane-local C-S bound (query = mt*16 + l15) ----
  bf16x8 qh[4], ql[4];
  float Mq[4];
  float km2 = kmax2[g * 4 + h];
#pragma unroll
  for (int mt = 0; mt < 4; mt++) {
    size_t qoff = (gbase + qb + mt * 16 + l15) * 768 + (size_t)h * 64 + quad * 8;
    u16x8 hh = *(const u16x8*)(qvs + qoff);
    u16x8 ll = *(const u16x8*)(qvs + qoff + 32);
    qh[mt] = __builtin_bit_cast(bf16x8, hh);
    ql[mt] = __builtin_bit_cast(bf16x8, ll);
    float s = 0.0f;
#pragma unroll
    for (int j = 0; j < 8; j++) {
      float v = bf2f(hh[j]) + bf2f(ll[j]);
      s = fmaf(v, v, s);
    }
    s += __shfl_xor(s, 16);
    s += __shfl_xor(s, 32);
    Mq[mt] = cf * sqrtf(s * km2);  // full |q| for THIS lane's query
  }

  f32x4 Oa[4][3];
#pragma unroll
  for (int mt = 0; mt < 4; mt++)
#pragma unroll
    for (int nt = 0; nt < 3; nt++) Oa[mt][nt] = (f32x4)0.0f;

  // ones rows for the l-column (dv=32), both buffers, once: threads 64-71
  if (t >= 64 && t < 72) {
    int u = t - 64;
    int bsel = u >> 2;
    int i = u & 3;
    u16x8 ones;
#pragma unroll
    for (int j = 0; j < 8; j++) ones[j] = 0x3F80;
    *(u16x8*)&Vh[bsel][32][i * 8] = ones;
  }

  // staging roles: threads 128-255 stage K (32 rows x 4 dim-segments, PERMUTED);
  // threads 0-63 stage V^T (natural key order)
  bool isK = (t >= 128);
  bool isV = (t < 64);
  u16x8 kreg_h, kreg_l;
  ushort4 vreg_h[4], vreg_l[4];
  int kkey = 0, kds = 0, kphys = 0, vkeyb = 0, vdvb = 0;
  if (isK) {
    int t2 = t - 128;
    kkey = t2 >> 2;                      // K-row rho
    kds = (t2 & 3) * 8;
    int nt_ = kkey >> 4, q_ = (kkey >> 2) & 3, r_ = kkey & 3;
    int p_ = (nt_ << 1) | (r_ >> 1);
    kphys = 8 * (q_ ^ p_) + 2 * p_ + (r_ & 1);  // chunk key stored in this row
  } else if (isV) {
    vkeyb = (t & 7) * 4;
    vdvb = (t >> 3) * 4;
  }

  auto load_chunk = [&](int c) {
    if (isK) {
      size_t ko = (gbase + (size_t)(c * 32 + kphys)) * 768 + (size_t)(4 + h) * 64 + kds;
      kreg_h = *(const u16x8*)(qvs + ko);
      kreg_l = *(const u16x8*)(qvs + ko + 32);
    } else if (isV) {
#pragma unroll
      for (int r = 0; r < 4; r++) {
        size_t vo = (gbase + (size_t)(c * 32 + vkeyb + r)) * 768 + (size_t)(8 + h) * 64 + vdvb;
        vreg_h[r] = *(const ushort4*)(qvs + vo);
        vreg_l[r] = *(const ushort4*)(qvs + vo + 32);
      }
    }
  };

  auto stage_chunk = [&](int bsel) {
    if (isK) {
      *(u16x8*)&Kh[bsel][kkey][kds] = kreg_h;
      *(u16x8*)&Kl[bsel][kkey][kds] = kreg_l;
    } else if (isV) {
      unsigned short ha[4][4], la[4][4];
#pragma unroll
      for (int r = 0; r < 4; r++) {
        *(ushort4*)&ha[r][0] = vreg_h[r];
        *(ushort4*)&la[r][0] = vreg_l[r];
      }
#pragma unroll
      for (int c2 = 0; c2 < 4; c2++) {
        ushort4 hv, lv;
        hv.x = ha[0][c2]; hv.y = ha[1][c2]; hv.z = ha[2][c2]; hv.w = ha[3][c2];
        lv.x = la[0][c2]; lv.y = la[1][c2]; lv.z = la[2][c2]; lv.w = la[3][c2];
        *(ushort4*)&Vh[bsel][vdvb + c2][vkeyb] = hv;
        *(ushort4*)&Vl[bsel][vdvb + c2][vkeyb] = lv;
      }
    }
  };

  // prologue: chunk 0 into buf 0
  load_chunk(0);
  stage_chunk(0);
  __syncthreads();

  int p = 0;
  for (int c = 0; c < 16; c++) {
    // ---- issue next chunk's loads first: latency hides under the compute below ----
    if (c < 15) load_chunk(c + 1);

    // ---- hoisted K and V fragments from LDS buf p ----
    bf16x8 akh[2], akl[2];
    akh[0] = *(const bf16x8*)&Kh[p][l15][quad * 8];
    akh[1] = *(const bf16x8*)&Kh[p][16 + l15][quad * 8];
    akl[0] = *(const bf16x8*)&Kl[p][l15][quad * 8];
    akl[1] = *(const bf16x8*)&Kl[p][16 + l15][quad * 8];
    bf16x8 bvh0 = *(const bf16x8*)&Vh[p][l15][quad * 8];
    bf16x8 bvl0 = *(const bf16x8*)&Vl[p][l15][quad * 8];
    bf16x8 bvh1 = *(const bf16x8*)&Vh[p][16 + l15][quad * 8];
    bf16x8 bvl1 = *(const bf16x8*)&Vl[p][16 + l15][quad * 8];
    bf16x8 bvh2 = *(const bf16x8*)&Vh[p][32 + l15][quad * 8];  // l15>0 reads junk -> cols discarded

#pragma unroll
    for (int mt = 0; mt < 4; mt++) {
      // ---- QK^T swapped: S'[key][query], this lane's col = its own query ----
      unsigned pkh[4], pkl[4];
#pragma unroll
      for (int nt = 0; nt < 2; nt++) {
        f32x4 S = (f32x4)0.0f;
        S = __builtin_amdgcn_mfma_f32_16x16x32_bf16(akh[nt], qh[mt], S, 0, 0, 0);
        S = __builtin_amdgcn_mfma_f32_16x16x32_bf16(akh[nt], ql[mt], S, 0, 0, 0);
        S = __builtin_amdgcn_mfma_f32_16x16x32_bf16(akl[nt], qh[mt], S, 0, 0, 0);
        S = __builtin_amdgcn_mfma_f32_16x16x32_bf16(akl[nt], ql[mt], S, 0, 0, 0);
        unsigned short h0, l0, h1, l1, h2, l2, h3, l3;
        split_bf_fast(__builtin_exp2f(fmaf(S[0], cf, -Mq[mt])), h0, l0);
        split_bf_fast(__builtin_exp2f(fmaf(S[1], cf, -Mq[mt])), h1, l1);
        split_bf_fast(__builtin_exp2f(fmaf(S[2], cf, -Mq[mt])), h2, l2);
        split_bf_fast(__builtin_exp2f(fmaf(S[3], cf, -Mq[mt])), h3, l3);
        pkh[nt * 2]     = (unsigned)h0 | ((unsigned)h1 << 16);
        pkh[nt * 2 + 1] = (unsigned)h2 | ((unsigned)h3 << 16);
        pkl[nt * 2]     = (unsigned)l0 | ((unsigned)l1 << 16);
        pkl[nt * 2 + 1] = (unsigned)l2 | ((unsigned)l3 << 16);
      }
      // ---- exchange: slot p routes quad -> quad^p; received slot p = frag u32 p ----
      u32x4 uh, ul;
      uh[0] = pkh[0];
      uh[1] = (unsigned)__shfl_xor((int)pkh[1], 16, 64);
      uh[2] = (unsigned)__shfl_xor((int)pkh[2], 32, 64);
      uh[3] = (unsigned)__shfl_xor((int)pkh[3], 48, 64);
      ul[0] = pkl[0];
      ul[1] = (unsigned)__shfl_xor((int)pkl[1], 16, 64);
      ul[2] = (unsigned)__shfl_xor((int)pkl[2], 32, 64);
      ul[3] = (unsigned)__shfl_xor((int)pkl[3], 48, 64);
      bf16x8 pa_h = __builtin_bit_cast(bf16x8, uh);
      bf16x8 pa_l = __builtin_bit_cast(bf16x8, ul);

      // ---- PV accumulate for this mt ----
      Oa[mt][0] = __builtin_amdgcn_mfma_f32_16x16x32_bf16(pa_h, bvh0, Oa[mt][0], 0, 0, 0);
      Oa[mt][0] = __builtin_amdgcn_mfma_f32_16x16x32_bf16(pa_h, bvl0, Oa[mt][0], 0, 0, 0);
      Oa[mt][0] = __builtin_amdgcn_mfma_f32_16x16x32_bf16(pa_l, bvh0, Oa[mt][0], 0, 0, 0);
      Oa[mt][1] = __builtin_amdgcn_mfma_f32_16x16x32_bf16(pa_h, bvh1, Oa[mt][1], 0, 0, 0);
      Oa[mt][1] = __builtin_amdgcn_mfma_f32_16x16x32_bf16(pa_h, bvl1, Oa[mt][1], 0, 0, 0);
      Oa[mt][1] = __builtin_amdgcn_mfma_f32_16x16x32_bf16(pa_l, bvh1, Oa[mt][1], 0, 0, 0);
      Oa[mt][2] = __builtin_amdgcn_mfma_f32_16x16x32_bf16(pa_h, bvh2, Oa[mt][2], 0, 0, 0);
      Oa[mt][2] = __builtin_amdgcn_mfma_f32_16x16x32_bf16(pa_l, bvh2, Oa[mt][2], 0, 0, 0);
    }

    // ---- write prefetched chunk c+1 into the other buffer, then single barrier ----
    if (c < 15) stage_chunk(p ^ 1);
    __syncthreads();
    p ^= 1;
  }

  // ---- epilogue: waves take turns on the shared Ot scratch (transpose + normalize) ----
  for (int w = 0; w < 4; w++) {
    if (wave == w) {
#pragma unroll
      for (int mt = 0; mt < 4; mt++) {
#pragma unroll
        for (int r = 0; r < 4; r++) {
          int row = mt * 16 + quad * 4 + r;
          Ot[row * 36 + l15] = Oa[mt][0][r];
          Ot[row * 36 + 16 + l15] = Oa[mt][1][r];
          if (l15 == 0) Ot[row * 36 + 32] = Oa[mt][2][r];  // l = ones-column
        }
      }
      int row = lane;  // wave's query row
      float inv = 1.0f / Ot[row * 36 + 32];
      size_t node = gbase + qb + row;
      u16x8 vh, vl;
#pragma unroll
      for (int seg = 0; seg < 4; seg++) {
#pragma unroll
        for (int j = 0; j < 8; j++) {
          unsigned short hi_, lo_;
          split_bf_fast(Ot[row * 36 + seg * 8 + j] * inv, hi_, lo_);
          vh[j] = hi_;
          vl[j] = lo_;
        }
        *(u16x8*)(ohi + node * 128 + h * 32 + seg * 8) = vh;
        *(u16x8*)(olo + node * 128 + h * 32 + seg * 8) = vl;
      }
    }
    __syncthreads();
  }
}

extern "C" void kernel_launch(void* const* d_in, const int* in_sizes, int n_in,
                              void* d_out, int out_size, void* d_ws, size_t ws_size,
                              hipStream_t stream) {
  (void)in_sizes; (void)n_in; (void)out_size; (void)ws_size;
  const float* x          = (const float*)d_in[0];
  const float* W0         = (const float*)d_in[1];
  const float* b0         = (const float*)d_in[2];
  const float* Wh         = (const float*)d_in[3];
  const float* bh         = (const float*)d_in[4];
  const float* bn_gamma   = (const float*)d_in[5];
  const float* bn_beta    = (const float*)d_in[6];
  const float* bn_mean    = (const float*)d_in[7];
  const float* bn_var     = (const float*)d_in[8];
  const float* attn_in_w  = (const float*)d_in[9];
  const float* attn_in_b  = (const float*)d_in[10];
  const float* attn_out_w = (const float*)d_in[11];
  const float* attn_out_b = (const float*)d_in[12];
  const int* edge_index   = (const int*)d_in[13];
  const int* src = edge_index;
  const int* dst = edge_index + N_EDGES;

  char* ws = (char*)d_ws;
  size_t off = 0;
  auto alloc = [&](size_t bytes) -> void* {
    void* p = ws + off;
    off += (bytes + 255) & ~(size_t)255;
    return p;
  };
  int*   deg     = (int*)alloc((size_t)N_NODES * 4);
  int*   offsets = (int*)alloc((size_t)(N_NODES + 1) * 4);
  int*   cursor  = (int*)alloc((size_t)N_NODES * 4);
  int*   csr     = (int*)alloc((size_t)N_EDGES * 4);
  float* dis     = (float*)alloc((size_t)N_NODES * 4);
  float* bufA    = (float*)alloc((size_t)N_NODES * HID * 4);   // h fp32; later f_hi/f_lo
  unsigned short* zhi = (unsigned short*)alloc((size_t)N_NODES * HID * 2);  // also o_hi
  unsigned short* zlo = (unsigned short*)alloc((size_t)N_NODES * HID * 2);  // also o_lo
  unsigned short* qvs = (unsigned short*)alloc((size_t)N_NODES * 768 * 2);  // qkv grouped hi/lo
  float* kmax2   = (float*)alloc((size_t)N_GRAPHS * 4 * 4);
  unsigned short* w0h = (unsigned short*)alloc(8192 * 2);
  unsigned short* w0l = (unsigned short*)alloc(8192 * 2);
  unsigned short* whh[3], *whl[3];
  for (int i = 0; i < 3; i++) {
    whh[i] = (unsigned short*)alloc(16384 * 2);
    whl[i] = (unsigned short*)alloc(16384 * 2);
  }
  unsigned short* wqh = (unsigned short*)alloc(49152 * 2);
  unsigned short* wql = (unsigned short*)alloc(49152 * 2);
  unsigned short* woh = (unsigned short*)alloc(16384 * 2);
  unsigned short* wol = (unsigned short*)alloc(16384 * 2);

  unsigned short* fhi = (unsigned short*)bufA;
  unsigned short* flo = fhi + (size_t)N_NODES * HID;

  float* fin = (float*)d_out;                       // [N, HID]
  float* emb = fin + (size_t)N_NODES * HID;         // [G, HID]

  hipMemsetAsync(deg, 0, (size_t)N_NODES * 4, stream);
  hipMemsetAsync(emb, 0, (size_t)N_GRAPHS * HID * 4, stream);
  hist_kernel<<<N_EDGES / 256, 256, 0, stream>>>(dst, deg);
  dis_kernel<<<N_NODES / 256, 256, 0, stream>>>(deg, dis);
  scan_kernel<<<1, 1024, 0, stream>>>(deg, offsets, cursor);
  fill_kernel<<<N_EDGES / 256, 256, 0, stream>>>(src, dst, cursor, csr);

  wprep_kernel<false><<<4, 256, 0, stream>>>(W0, 64, 128, w0h, w0l);
  for (int i = 0; i < 3; i++)
    wprep_kernel<false><<<8, 256, 0, stream>>>(Wh + (size_t)i * HID * HID, 128, 128,
                                               whh[i], whl[i]);
  wprep_kernel<true><<<24, 256, 0, stream>>>(attn_in_w, 128, 384, wqh, wql);
  wprep_kernel<true><<<8, 256, 0, stream>>>(attn_out_w, 128, 128, woh, wol);

  dim3 ggrid(N_NODES / 128, 1);
  agg64_kernel<<<N_NODES / 4, 256, 0, stream>>>(x, dis, offsets, csr, zhi, zlo);
  gemm_mfma<64, 128, true, true, false, false><<<ggrid, 256, 0, stream>>>(
      zhi, zlo, w0h, w0l, b0, bn_gamma, bn_beta, bn_mean, bn_var, bufA, nullptr, nullptr);
  for (int L = 0; L < 2; L++) {
    agg128_kernel<<<N_NODES / 4, 256, 0, stream>>>(bufA, dis, offsets, csr, zhi, zlo);
    gemm_mfma<128, 128, true, true, false, false><<<ggrid, 256, 0, stream>>>(
        zhi, zlo, whh[L], whl[L], bh + (size_t)L * HID,
        bn_gamma + (size_t)(L + 1) * HID, bn_beta + (size_t)(L + 1) * HID,
        bn_mean + (size_t)(L + 1) * HID, bn_var + (size_t)(L + 1) * HID,
        bufA, nullptr, nullptr);
  }
  agg128_kernel<<<N_NODES / 4, 256, 0, stream>>>(bufA, dis, offsets, csr, zhi, zlo);
  gemm_mfma<128, 128, true, true, true, false><<<ggrid, 256, 0, stream>>>(
      zhi, zlo, whh[2], whl[2], bh + (size_t)2 * HID,
      bn_gamma + (size_t)3 * HID, bn_beta + (size_t)3 * HID,
      bn_mean + (size_t)3 * HID, bn_var + (size_t)3 * HID,
      nullptr, fhi, flo);
  dim3 qgrid(N_NODES / 128, 3);
  gemm_mfma<128, 384, false, false, true, true><<<qgrid, 256, 0, stream>>>(
      fhi, flo, wqh, wql, attn_in_b, nullptr, nullptr, nullptr, nullptr,
      nullptr, qvs, nullptr);
  knorm_kernel<<<N_GRAPHS * 4, 256, 0, stream>>>(qvs, kmax2);
  attn_mfma_kernel<<<N_GRAPHS * 4 * 2, 256, 0, stream>>>(qvs, kmax2, zhi, zlo);
  gemm_mfma<128, 128, false, false, false, false, true><<<ggrid, 256, 0, stream>>>(
      zhi, zlo, woh, wol, attn_out_b, nullptr, nullptr, nullptr, nullptr,
      fin, nullptr, nullptr, emb);
}